// Round 1
// baseline (274.347 us; speedup 1.0000x reference)
//
#include <hip/hip_runtime.h>
#include <hip/hip_bf16.h>

#define NS 8192
#define NQ 8192
#define NTOT 16384
#define KDIM 1024
#define ED 512
#define NC 64

typedef __attribute__((ext_vector_type(4))) float fx4;
typedef __attribute__((ext_vector_type(4))) int ix4;
typedef __attribute__((ext_vector_type(8))) short sx8;
typedef __attribute__((ext_vector_type(4))) unsigned short ux4;
typedef __attribute__((ext_vector_type(8))) unsigned short ux8;

__device__ __forceinline__ unsigned short f2bf(float f) {
  union { float f; unsigned u; } v; v.f = f;
  unsigned r = v.u + 0x7fffu + ((v.u >> 16) & 1u);   // RNE
  return (unsigned short)(r >> 16);
}
__device__ __forceinline__ float bf2f(unsigned short h) {
  union { unsigned u; float f; } v; v.u = ((unsigned)h) << 16;
  return v.f;
}

// ---------------------------------------------------------------------------
// K0: W [1024,512] fp32 row-major -> Wt [512,1024] bf16 (B^T / N-major layout)
// ---------------------------------------------------------------------------
__global__ __launch_bounds__(256) void k_transpose_w(const float* __restrict__ W,
                                                     unsigned short* __restrict__ Wt) {
  __shared__ float tile[32][33];  // +1 pad: conflict-free transpose
  int k0 = blockIdx.x * 32;       // over KDIM
  int n0 = blockIdx.y * 32;       // over ED
  int tx = threadIdx.x & 31;
  int ty = threadIdx.x >> 5;      // 0..7
#pragma unroll
  for (int i = ty; i < 32; i += 8)
    tile[i][tx] = W[(size_t)(k0 + i) * ED + n0 + tx];
  __syncthreads();
#pragma unroll
  for (int i = ty; i < 32; i += 8)
    Wt[(size_t)(n0 + i) * KDIM + k0 + tx] = f2bf(tile[tx][i]);
}

// ---------------------------------------------------------------------------
// K1: emb = X @ W, X = concat(support, query) [16384,1024] fp32, output bf16.
// 128x128 tile, 16x16x32 bf16 MFMA, fused fp32->bf16 conversion staging.
// LDS layout [quad][row][8 bf16] -> ds_read_b128 fragments, conflict-free.
// XCD swizzle: the 4 n-blocks sharing an A-slice land on one XCD (L2 reuse).
// ---------------------------------------------------------------------------
__global__ __launch_bounds__(256) void k_gemm_embed(
    const float* __restrict__ Xs, const float* __restrict__ Xq,
    const unsigned short* __restrict__ Wt, unsigned short* __restrict__ embU) {
  __shared__ unsigned short Ash[4 * 128 * 8];  // 8 KB
  __shared__ unsigned short Bsh[4 * 128 * 8];  // 8 KB

  int lid = blockIdx.x;           // 0..511
  int x = lid & 7;                // xcd (round-robin dispatch heuristic)
  int s = lid >> 3;               // 0..63
  int m_blk = x * 16 + (s >> 2);  // 0..127
  int n_blk = s & 3;              // 0..3

  const float* X = (m_blk < 64) ? Xs : Xq;
  int row0 = (m_blk & 63) * 128;

  int t = threadIdx.x;
  int lane = t & 63, w = t >> 6;
  int wm = w >> 1, wn = w & 1;
  int quad = lane >> 4, ml = lane & 15;

  fx4 acc[4][4];
#pragma unroll
  for (int i = 0; i < 4; ++i)
#pragma unroll
    for (int j = 0; j < 4; ++j) acc[i][j] = fx4{0.f, 0.f, 0.f, 0.f};

  for (int k0 = 0; k0 < KDIM; k0 += 32) {
    __syncthreads();
    // stage A: 128 rows x 32 k, fp32 -> bf16
#pragma unroll
    for (int c = 0; c < 4; ++c) {
      int ch = t + 256 * c;           // 0..1023
      int m = ch >> 3, kq = ch & 7;   // k offset = kq*4
      fx4 v = *(const fx4*)&X[(size_t)(row0 + m) * KDIM + k0 + kq * 4];
      ux4 b;
      b.x = f2bf(v.x); b.y = f2bf(v.y); b.z = f2bf(v.z); b.w = f2bf(v.w);
      int qd = kq >> 1, j0 = (kq & 1) * 4;
      *(ux4*)&Ash[(qd * 128 + m) * 8 + j0] = b;
    }
    // stage B: 128 n-rows x 32 k bf16 straight copy (16B chunks)
#pragma unroll
    for (int c = 0; c < 2; ++c) {
      int ch = t + 256 * c;           // 0..511
      int n = ch >> 2, q = ch & 3;
      *(ix4*)&Bsh[(q * 128 + n) * 8] =
          *(const ix4*)&Wt[(size_t)(n_blk * 128 + n) * KDIM + k0 + q * 8];
    }
    __syncthreads();

    sx8 af[4], bfr[4];
#pragma unroll
    for (int i = 0; i < 4; ++i)
      af[i] = *(const sx8*)&Ash[(quad * 128 + wm * 64 + i * 16 + ml) * 8];
#pragma unroll
    for (int i = 0; i < 4; ++i)
      bfr[i] = *(const sx8*)&Bsh[(quad * 128 + wn * 64 + i * 16 + ml) * 8];
#pragma unroll
    for (int i = 0; i < 4; ++i)
#pragma unroll
      for (int j = 0; j < 4; ++j)
        acc[i][j] = __builtin_amdgcn_mfma_f32_16x16x32_bf16(af[i], bfr[j], acc[i][j], 0, 0, 0);
  }

  int grow0 = m_blk * 128 + wm * 64;
  int gcol0 = n_blk * 128 + wn * 64;
#pragma unroll
  for (int i = 0; i < 4; ++i)
#pragma unroll
    for (int j = 0; j < 4; ++j)
#pragma unroll
      for (int r = 0; r < 4; ++r)
        embU[(size_t)(grow0 + i * 16 + quad * 4 + r) * ED + gcol0 + j * 16 + ml] =
            f2bf(acc[i][j][r]);
}

// ---------------------------------------------------------------------------
// K2: row L2-normalize (bf16 in, bf16 out) + fused prototype accumulation via
// fp32 global atomics for support rows. One wave per row.
// ---------------------------------------------------------------------------
__global__ __launch_bounds__(256) void k_normalize(
    const unsigned short* __restrict__ embU, const int* __restrict__ labels,
    unsigned short* __restrict__ nrm, float* __restrict__ P) {
  int w = threadIdx.x >> 6, lane = threadIdx.x & 63;
  int row = blockIdx.x * 4 + w;
  ux8 e = *(const ux8*)&embU[(size_t)row * ED + lane * 8];
  float v[8];
  float ssq = 0.f;
#pragma unroll
  for (int i = 0; i < 8; ++i) { v[i] = bf2f(e[i]); ssq += v[i] * v[i]; }
#pragma unroll
  for (int off = 32; off >= 1; off >>= 1) ssq += __shfl_xor(ssq, off, 64);
  float scale = 1.0f / fmaxf(sqrtf(ssq), 1e-12f);
  ux8 o;
#pragma unroll
  for (int i = 0; i < 8; ++i) { v[i] *= scale; o[i] = f2bf(v[i]); }
  *(ux8*)&nrm[(size_t)row * ED + lane * 8] = o;
  if (row < NS) {
    int lbl = labels[row];
    float* p = P + (size_t)lbl * ED + lane * 8;
#pragma unroll
    for (int i = 0; i < 8; ++i) atomicAdd(p + i, v[i]);
  }
}

// ---------------------------------------------------------------------------
// K3: class_scores = q_norm @ P^T via MFMA (K=512), fused stable softmax.
// P (64x512) staged once into LDS as bf16 B-fragments (exactly 64 KB).
// Each wave: 16 queries x 64 classes. A-fragments read straight from global.
// ---------------------------------------------------------------------------
__global__ __launch_bounds__(256) void k_scores(
    const unsigned short* __restrict__ nrmQ,  // [8192,512] bf16
    const float* __restrict__ P,              // [64,512] fp32
    float* __restrict__ out) {                // [8192,64] fp32
  __shared__ unsigned short Pl[64 * 64 * 8];  // [kq][n][8] = 64 KB

  int t = threadIdx.x;
  // stage P -> LDS bf16, chunk = 8 k-elems of one class row
#pragma unroll
  for (int i = 0; i < 16; ++i) {
    int ch = t + 256 * i;          // 0..4095
    int n = ch & 63, kq = ch >> 6; // class row, k-chunk
    fx4 a = *(const fx4*)&P[(size_t)n * ED + kq * 8];
    fx4 b = *(const fx4*)&P[(size_t)n * ED + kq * 8 + 4];
    ux8 o;
    o[0] = f2bf(a.x); o[1] = f2bf(a.y); o[2] = f2bf(a.z); o[3] = f2bf(a.w);
    o[4] = f2bf(b.x); o[5] = f2bf(b.y); o[6] = f2bf(b.z); o[7] = f2bf(b.w);
    *(ux8*)&Pl[ch * 8] = o;
  }
  __syncthreads();

  int lane = t & 63, w = t >> 6;
  int quad = lane >> 4, ml = lane & 15;
  int qrow0 = blockIdx.x * 64 + w * 16;

  fx4 acc[4];
#pragma unroll
  for (int i = 0; i < 4; ++i) acc[i] = fx4{0.f, 0.f, 0.f, 0.f};

  for (int ki = 0; ki < 16; ++ki) {
    sx8 a = *(const sx8*)&nrmQ[(size_t)(qrow0 + ml) * ED + ki * 32 + quad * 8];
#pragma unroll
    for (int nt = 0; nt < 4; ++nt) {
      sx8 b = *(const sx8*)&Pl[((ki * 4 + quad) * 64 + nt * 16 + ml) * 8];
      acc[nt] = __builtin_amdgcn_mfma_f32_16x16x32_bf16(a, b, acc[nt], 0, 0, 0);
    }
  }

  // softmax over 64 classes; row r lives in the 16 lanes of this quad-group
#pragma unroll
  for (int r = 0; r < 4; ++r) {
    float m = fmaxf(fmaxf(acc[0][r], acc[1][r]), fmaxf(acc[2][r], acc[3][r]));
#pragma unroll
    for (int off = 1; off < 16; off <<= 1) m = fmaxf(m, __shfl_xor(m, off, 16));
    float e[4], ssum = 0.f;
#pragma unroll
    for (int nt = 0; nt < 4; ++nt) { e[nt] = __expf(acc[nt][r] - m); ssum += e[nt]; }
#pragma unroll
    for (int off = 1; off < 16; off <<= 1) ssum += __shfl_xor(ssum, off, 16);
    float inv = 1.0f / ssum;
    int qq = qrow0 + quad * 4 + r;
#pragma unroll
    for (int nt = 0; nt < 4; ++nt)
      out[(size_t)qq * NC + nt * 16 + ml] = e[nt] * inv;
  }
}

// ---------------------------------------------------------------------------
extern "C" void kernel_launch(void* const* d_in, const int* in_sizes, int n_in,
                              void* d_out, int out_size, void* d_ws, size_t ws_size,
                              hipStream_t stream) {
  const float* Xs     = (const float*)d_in[0];  // support_data [8192,1024]
  const int*   labels = (const int*)d_in[1];    // support_labels [8192]
  const float* Xq     = (const float*)d_in[2];  // query_data [8192,1024]
  const float* W      = (const float*)d_in[3];  // W [1024,512]
  float* out = (float*)d_out;

  char* ws = (char*)d_ws;
  unsigned short* Wt   = (unsigned short*)ws;                         // 1 MB
  unsigned short* embU = (unsigned short*)(ws + (1u << 20));          // 16 MB
  unsigned short* nrm  = (unsigned short*)(ws + (1u << 20) + (size_t)NTOT * ED * 2);
  float* P = (float*)(ws + (1u << 20) + 2 * (size_t)NTOT * ED * 2);   // 128 KB

  // ws is re-poisoned before every call: zero P explicitly (capture-safe).
  hipMemsetAsync(P, 0, (size_t)NC * ED * sizeof(float), stream);

  k_transpose_w<<<dim3(KDIM / 32, ED / 32), 256, 0, stream>>>(W, Wt);
  k_gemm_embed<<<512, 256, 0, stream>>>(Xs, Xq, Wt, embU);
  k_normalize<<<NTOT / 4, 256, 0, stream>>>(embU, labels, nrm, P);
  k_scores<<<NQ / 64, 256, 0, stream>>>(nrm + (size_t)NS * ED, P, out);
}

// Round 2
// 204.625 us; speedup vs baseline: 1.3407x; 1.3407x over previous
//
#include <hip/hip_runtime.h>
#include <hip/hip_bf16.h>

#define NS 8192
#define NQ 8192
#define NTOT 16384
#define KDIM 1024
#define ED 512
#define NC 64
#define PBLK 64   // k_proto_partial blocks along support dim

typedef __attribute__((ext_vector_type(4))) float fx4;
typedef __attribute__((ext_vector_type(4))) int ix4;
typedef __attribute__((ext_vector_type(8))) short sx8;
typedef __attribute__((ext_vector_type(4))) unsigned short ux4;
typedef __attribute__((ext_vector_type(8))) unsigned short ux8;

__device__ __forceinline__ unsigned short f2bf(float f) {
  union { float f; unsigned u; } v; v.f = f;
  unsigned r = v.u + 0x7fffu + ((v.u >> 16) & 1u);   // RNE
  return (unsigned short)(r >> 16);
}
__device__ __forceinline__ float bf2f(unsigned short h) {
  union { unsigned u; float f; } v; v.u = ((unsigned)h) << 16;
  return v.f;
}

// ---------------------------------------------------------------------------
// K0: W [1024,512] fp32 row-major -> Wt [512,1024] bf16 (B^T / N-major layout)
// ---------------------------------------------------------------------------
__global__ __launch_bounds__(256) void k_transpose_w(const float* __restrict__ W,
                                                     unsigned short* __restrict__ Wt) {
  __shared__ float tile[32][33];  // +1 pad: conflict-free transpose
  int k0 = blockIdx.x * 32;       // over KDIM
  int n0 = blockIdx.y * 32;       // over ED
  int tx = threadIdx.x & 31;
  int ty = threadIdx.x >> 5;      // 0..7
#pragma unroll
  for (int i = ty; i < 32; i += 8)
    tile[i][tx] = W[(size_t)(k0 + i) * ED + n0 + tx];
  __syncthreads();
#pragma unroll
  for (int i = ty; i < 32; i += 8)
    Wt[(size_t)(n0 + i) * KDIM + k0 + tx] = f2bf(tile[tx][i]);
}

// ---------------------------------------------------------------------------
// K1: emb = X @ W, X = concat(support, query) [16384,1024] fp32, output bf16.
// 128x128 tile, 16x16x32 bf16 MFMA, fused fp32->bf16 conversion staging.
// XCD swizzle: the 4 n-blocks sharing an A-slice land on one XCD (L2 reuse).
// ---------------------------------------------------------------------------
__global__ __launch_bounds__(256) void k_gemm_embed(
    const float* __restrict__ Xs, const float* __restrict__ Xq,
    const unsigned short* __restrict__ Wt, unsigned short* __restrict__ embU) {
  __shared__ unsigned short Ash[4 * 128 * 8];  // 8 KB
  __shared__ unsigned short Bsh[4 * 128 * 8];  // 8 KB

  int lid = blockIdx.x;           // 0..511
  int x = lid & 7;                // xcd (round-robin dispatch heuristic)
  int s = lid >> 3;               // 0..63
  int m_blk = x * 16 + (s >> 2);  // 0..127
  int n_blk = s & 3;              // 0..3

  const float* X = (m_blk < 64) ? Xs : Xq;
  int row0 = (m_blk & 63) * 128;

  int t = threadIdx.x;
  int lane = t & 63, w = t >> 6;
  int wm = w >> 1, wn = w & 1;
  int quad = lane >> 4, ml = lane & 15;

  fx4 acc[4][4];
#pragma unroll
  for (int i = 0; i < 4; ++i)
#pragma unroll
    for (int j = 0; j < 4; ++j) acc[i][j] = fx4{0.f, 0.f, 0.f, 0.f};

  for (int k0 = 0; k0 < KDIM; k0 += 32) {
    __syncthreads();
    // stage A: 128 rows x 32 k, fp32 -> bf16
#pragma unroll
    for (int c = 0; c < 4; ++c) {
      int ch = t + 256 * c;           // 0..1023
      int m = ch >> 3, kq = ch & 7;   // k offset = kq*4
      fx4 v = *(const fx4*)&X[(size_t)(row0 + m) * KDIM + k0 + kq * 4];
      ux4 b;
      b.x = f2bf(v.x); b.y = f2bf(v.y); b.z = f2bf(v.z); b.w = f2bf(v.w);
      int qd = kq >> 1, j0 = (kq & 1) * 4;
      *(ux4*)&Ash[(qd * 128 + m) * 8 + j0] = b;
    }
    // stage B: 128 n-rows x 32 k bf16 straight copy (16B chunks)
#pragma unroll
    for (int c = 0; c < 2; ++c) {
      int ch = t + 256 * c;           // 0..511
      int n = ch >> 2, q = ch & 3;
      *(ix4*)&Bsh[(q * 128 + n) * 8] =
          *(const ix4*)&Wt[(size_t)(n_blk * 128 + n) * KDIM + k0 + q * 8];
    }
    __syncthreads();

    sx8 af[4], bfr[4];
#pragma unroll
    for (int i = 0; i < 4; ++i)
      af[i] = *(const sx8*)&Ash[(quad * 128 + wm * 64 + i * 16 + ml) * 8];
#pragma unroll
    for (int i = 0; i < 4; ++i)
      bfr[i] = *(const sx8*)&Bsh[(quad * 128 + wn * 64 + i * 16 + ml) * 8];
#pragma unroll
    for (int i = 0; i < 4; ++i)
#pragma unroll
      for (int j = 0; j < 4; ++j)
        acc[i][j] = __builtin_amdgcn_mfma_f32_16x16x32_bf16(af[i], bfr[j], acc[i][j], 0, 0, 0);
  }

  int grow0 = m_blk * 128 + wm * 64;
  int gcol0 = n_blk * 128 + wn * 64;
#pragma unroll
  for (int i = 0; i < 4; ++i)
#pragma unroll
    for (int j = 0; j < 4; ++j)
#pragma unroll
      for (int r = 0; r < 4; ++r)
        embU[(size_t)(grow0 + i * 16 + quad * 4 + r) * ED + gcol0 + j * 16 + ml] =
            f2bf(acc[i][j][r]);
}

// ---------------------------------------------------------------------------
// K2: row L2-normalize (bf16 in, bf16 out). One wave per row. NO atomics.
// ---------------------------------------------------------------------------
__global__ __launch_bounds__(256) void k_normalize(
    const unsigned short* __restrict__ embU, unsigned short* __restrict__ nrm) {
  int w = threadIdx.x >> 6, lane = threadIdx.x & 63;
  int row = blockIdx.x * 4 + w;
  ux8 e = *(const ux8*)&embU[(size_t)row * ED + lane * 8];
  float v[8];
  float ssq = 0.f;
#pragma unroll
  for (int i = 0; i < 8; ++i) { v[i] = bf2f(e[i]); ssq += v[i] * v[i]; }
#pragma unroll
  for (int off = 32; off >= 1; off >>= 1) ssq += __shfl_xor(ssq, off, 64);
  float scale = 1.0f / fmaxf(sqrtf(ssq), 1e-12f);
  ux8 o;
#pragma unroll
  for (int i = 0; i < 8; ++i) o[i] = f2bf(v[i] * scale);
  *(ux8*)&nrm[(size_t)row * ED + lane * 8] = o;
}

// ---------------------------------------------------------------------------
// K2b: per-class partial sums of normalized support rows, LDS-accumulated.
// Grid (PBLK, 2): blockIdx.x = support chunk (128 rows), blockIdx.y = dim half.
// LDS tile [64 classes][256 dims] fp32 = 64 KB. LDS atomics only (~2 same-class
// rows per block -> negligible contention). Writes partial slice to Ppart.
// ---------------------------------------------------------------------------
__global__ __launch_bounds__(256) void k_proto_partial(
    const unsigned short* __restrict__ nrmS, const int* __restrict__ labels,
    float* __restrict__ Ppart) {
  __shared__ float Pl[NC * 256];  // 64 KB
  int t = threadIdx.x;
#pragma unroll
  for (int i = 0; i < NC; ++i) Pl[i * 256 + t] = 0.f;
  __syncthreads();

  int w = t >> 6, lane = t & 63;
  int half = blockIdx.y;          // 0 or 1: dims [half*256, half*256+256)
  int row0 = blockIdx.x * (NS / PBLK);
  for (int r = w; r < NS / PBLK; r += 4) {
    int row = row0 + r;
    int lbl = labels[row];
    ux4 e = *(const ux4*)&nrmS[(size_t)row * ED + half * 256 + lane * 4];
    float* p = &Pl[lbl * 256 + lane * 4];
    atomicAdd(p + 0, bf2f(e.x));
    atomicAdd(p + 1, bf2f(e.y));
    atomicAdd(p + 2, bf2f(e.z));
    atomicAdd(p + 3, bf2f(e.w));
  }
  __syncthreads();

  // Ppart layout: [PBLK][NC][ED]; this block owns [bx][*][half*256 +: 256]
  float* o = Ppart + (size_t)blockIdx.x * NC * ED + half * 256;
#pragma unroll
  for (int i = 0; i < NC; ++i) o[(size_t)i * ED + t] = Pl[i * 256 + t];
}

// ---------------------------------------------------------------------------
// K2c: P[c][d] = sum over PBLK partial slices. Fully coalesced.
// ---------------------------------------------------------------------------
__global__ __launch_bounds__(256) void k_proto_reduce(
    const float* __restrict__ Ppart, float* __restrict__ P) {
  int i = blockIdx.x * 256 + threadIdx.x;  // 0 .. NC*ED-1
  float s = 0.f;
#pragma unroll 8
  for (int b = 0; b < PBLK; ++b) s += Ppart[(size_t)b * NC * ED + i];
  P[i] = s;
}

// ---------------------------------------------------------------------------
// K3: class_scores = q_norm @ P^T via MFMA (K=512), fused stable softmax.
// ---------------------------------------------------------------------------
__global__ __launch_bounds__(256) void k_scores(
    const unsigned short* __restrict__ nrmQ,  // [8192,512] bf16
    const float* __restrict__ P,              // [64,512] fp32
    float* __restrict__ out) {                // [8192,64] fp32
  __shared__ unsigned short Pl[64 * 64 * 8];  // [kq][n][8] = 64 KB

  int t = threadIdx.x;
#pragma unroll
  for (int i = 0; i < 16; ++i) {
    int ch = t + 256 * i;          // 0..4095
    int n = ch & 63, kq = ch >> 6; // class row, k-chunk
    fx4 a = *(const fx4*)&P[(size_t)n * ED + kq * 8];
    fx4 b = *(const fx4*)&P[(size_t)n * ED + kq * 8 + 4];
    ux8 o;
    o[0] = f2bf(a.x); o[1] = f2bf(a.y); o[2] = f2bf(a.z); o[3] = f2bf(a.w);
    o[4] = f2bf(b.x); o[5] = f2bf(b.y); o[6] = f2bf(b.z); o[7] = f2bf(b.w);
    *(ux8*)&Pl[ch * 8] = o;
  }
  __syncthreads();

  int lane = t & 63, w = t >> 6;
  int quad = lane >> 4, ml = lane & 15;
  int qrow0 = blockIdx.x * 64 + w * 16;

  fx4 acc[4];
#pragma unroll
  for (int i = 0; i < 4; ++i) acc[i] = fx4{0.f, 0.f, 0.f, 0.f};

  for (int ki = 0; ki < 16; ++ki) {
    sx8 a = *(const sx8*)&nrmQ[(size_t)(qrow0 + ml) * ED + ki * 32 + quad * 8];
#pragma unroll
    for (int nt = 0; nt < 4; ++nt) {
      sx8 b = *(const sx8*)&Pl[((ki * 4 + quad) * 64 + nt * 16 + ml) * 8];
      acc[nt] = __builtin_amdgcn_mfma_f32_16x16x32_bf16(a, b, acc[nt], 0, 0, 0);
    }
  }

  // softmax over 64 classes; row r lives in the 16 lanes of this quad-group
#pragma unroll
  for (int r = 0; r < 4; ++r) {
    float m = fmaxf(fmaxf(acc[0][r], acc[1][r]), fmaxf(acc[2][r], acc[3][r]));
#pragma unroll
    for (int off = 1; off < 16; off <<= 1) m = fmaxf(m, __shfl_xor(m, off, 16));
    float e[4], ssum = 0.f;
#pragma unroll
    for (int nt = 0; nt < 4; ++nt) { e[nt] = __expf(acc[nt][r] - m); ssum += e[nt]; }
#pragma unroll
    for (int off = 1; off < 16; off <<= 1) ssum += __shfl_xor(ssum, off, 16);
    float inv = 1.0f / ssum;
    int qq = qrow0 + quad * 4 + r;
#pragma unroll
    for (int nt = 0; nt < 4; ++nt)
      out[(size_t)qq * NC + nt * 16 + ml] = e[nt] * inv;
  }
}

// ---------------------------------------------------------------------------
extern "C" void kernel_launch(void* const* d_in, const int* in_sizes, int n_in,
                              void* d_out, int out_size, void* d_ws, size_t ws_size,
                              hipStream_t stream) {
  const float* Xs     = (const float*)d_in[0];  // support_data [8192,1024]
  const int*   labels = (const int*)d_in[1];    // support_labels [8192]
  const float* Xq     = (const float*)d_in[2];  // query_data [8192,1024]
  const float* W      = (const float*)d_in[3];  // W [1024,512]
  float* out = (float*)d_out;

  char* ws = (char*)d_ws;
  size_t off = 0;
  unsigned short* Wt   = (unsigned short*)(ws + off); off += (size_t)ED * KDIM * 2;      // 1 MB
  unsigned short* embU = (unsigned short*)(ws + off); off += (size_t)NTOT * ED * 2;      // 16 MB
  unsigned short* nrm  = (unsigned short*)(ws + off); off += (size_t)NTOT * ED * 2;      // 16 MB
  float* Ppart = (float*)(ws + off); off += (size_t)PBLK * NC * ED * 4;                  // 8 MB
  float* P     = (float*)(ws + off); off += (size_t)NC * ED * 4;                         // 128 KB

  k_transpose_w<<<dim3(KDIM / 32, ED / 32), 256, 0, stream>>>(W, Wt);
  k_gemm_embed<<<512, 256, 0, stream>>>(Xs, Xq, Wt, embU);
  k_normalize<<<NTOT / 4, 256, 0, stream>>>(embU, nrm);
  k_proto_partial<<<dim3(PBLK, 2), 256, 0, stream>>>(nrm, labels, Ppart);
  k_proto_reduce<<<NC * ED / 256, 256, 0, stream>>>(Ppart, P);
  k_scores<<<NQ / 64, 256, 0, stream>>>(nrm + (size_t)NS * ED, P, out);
}